// Round 5
// baseline (230.560 us; speedup 1.0000x reference)
//
#include <hip/hip_runtime.h>

typedef unsigned short u16;
typedef __attribute__((ext_vector_type(8))) short s16x8;
typedef __attribute__((ext_vector_type(4))) float f32x4;
typedef __attribute__((ext_vector_type(4))) unsigned int u32x4;

// f32 -> bf16 bits, round-to-nearest-even (finite values)
__device__ __forceinline__ u16 f2bf(float f) {
    unsigned u = __builtin_bit_cast(unsigned, f);
    u += 0x7fffu + ((u >> 16) & 1u);
    return (u16)(u >> 16);
}
__device__ __forceinline__ float lo_bf(unsigned v) {
    return __builtin_bit_cast(float, v << 16);
}
__device__ __forceinline__ float hi_bf(unsigned v) {
    return __builtin_bit_cast(float, v & 0xffff0000u);
}

// ws layout (floats): [0..127] Sx[n][c], [128..255] Sx2[n][c]
#define WS_SX   0
#define WS_SX2  128

// ---------------- Kernel 1: per-(n,c) moments of x (fp32) ----------------
__global__ __launch_bounds__(256) void k_reduce(const float* __restrict__ x,
                                                float* __restrict__ ws) {
    int nc = blockIdx.x;                       // 0..127, one 4096-elem channel each
    const f32x4* p = (const f32x4*)(x + (size_t)nc * 4096);
    int t = threadIdx.x;
    float s = 0.f, s2 = 0.f;
    for (int it = 0; it < 4; ++it) {
        f32x4 v = p[t + it * 256];
        for (int e = 0; e < 4; ++e) { s += v[e]; s2 += v[e] * v[e]; }
    }
    for (int off = 32; off; off >>= 1) {
        s  += __shfl_down(s, off);
        s2 += __shfl_down(s2, off);
    }
    __shared__ float rs[4], rs2[4];
    int lane = t & 63, wv = t >> 6;
    if (lane == 0) { rs[wv] = s; rs2[wv] = s2; }
    __syncthreads();
    if (t == 0) {
        ws[WS_SX  + nc] = rs[0] + rs[1] + rs[2] + rs[3];
        ws[WS_SX2 + nc] = rs2[0] + rs2[1] + rs2[2] + rs2[3];
    }
}

// ---------------- Kernel 2: fused stats + upsample + GN + pointwise --------
// Block = (n, dd, hq): dd in [0,64) output depth-row (d = dd>>2, i = dd&3),
// hq in [0,4) quarter of hh. Block's per-o region = 4 KiB CONTIGUOUS
// (16 hh rows x 64 ww). Round 5 (= Round-4 retry with safe LDS):
// aggregate ALL 4 stages in LDS for 16 o-rows at a time
// (stg[16][1024+pad] = 64.3 KiB, FOUR o-quarter passes, one mt each) so the
// store phase emits the FULL 4 KiB per o as 4 back-to-back 1 KiB wave
// stores (R1->R3: burst SIZE is the lever, ordering is not).
// Total LDS 91.3 KiB (proven envelope is 128 KiB) -> 1 block/CU.
// sA aliases into stg (dead after afrag build).
#define SWS 96        // sW/sX row stride in shorts (192 B: 2-way bank alias = free)
#define STG_LD 1028   // staging row stride in floats (4112 B, 16B-aligned, bank-spread)
__global__ __launch_bounds__(256, 1) void k_main(const float* __restrict__ x,
                                              const float* __restrict__ w_ct,
                                              const float* __restrict__ b_ct,
                                              const float* __restrict__ gamma,
                                              const float* __restrict__ beta,
                                              const float* __restrict__ w_pw,
                                              const float* __restrict__ ws,
                                              float* __restrict__ out) {
    __shared__ __align__(16) u16   sWb[64 * SWS];     // [ijk][c] bf16        (12 KiB)
    __shared__ __align__(16) u16   sXb[64 * SWS];     // [h_loc*16+w][c] bf16 (12 KiB)
    __shared__ __align__(16) float stg[16 * STG_LD];  // staging (64.3 KiB); sA aliases here
    __shared__ float sK[64];
    __shared__ float p_sw[256], p_sw2[256];           // partial w-moments [qr][c]
    __shared__ float s_b[64], s_g[64], s_be[64];
    __shared__ float s_mi[2];                         // mean, inv_std

    float* sA = stg;   // [o][c] fp32, stride 68 (4352 floats <= 16448) — dead before stg use

    int t = threadIdx.x;
    int B = blockIdx.x;
    int b = (B & 7) * 64 + (B >> 3);           // XCD-compact remap (bijective)
    int n = b >> 8, dd = (b >> 2) & 63, hq = b & 3;
    int d = dd >> 2, i_f = dd & 3;

    // ---- stage w_ct (transpose + bf16 + partial moments) ----
    {
        int c = t & 63, qr = t >> 6;               // 4 threads per channel
        const f32x4* wp = (const f32x4*)(w_ct + c * 64 + qr * 16);
        float sw = 0.f, sw2 = 0.f;
        for (int r = 0; r < 4; ++r) {
            f32x4 v = wp[r];
            for (int e = 0; e < 4; ++e) {
                float f = v[e];
                sw += f; sw2 += f * f;
                sWb[(qr * 16 + r * 4 + e) * SWS + c] = f2bf(f);
            }
        }
        p_sw[t] = sw; p_sw2[t] = sw2;
    }
    // ---- stage x rows: c = t&63, h_loc = t>>6 (4 h-rows of 16 w each) ----
    {
        int c = t & 63, h_loc = t >> 6;
        const f32x4* xp = (const f32x4*)(x + ((size_t)n * 64 + c) * 4096
                                           + d * 256 + (hq * 4 + h_loc) * 16);
        for (int r = 0; r < 4; ++r) {
            f32x4 v = xp[r];
            for (int e = 0; e < 4; ++e)
                sXb[(h_loc * 16 + r * 4 + e) * SWS + c] = f2bf(v[e]);
        }
    }
    if (t < 64) { s_b[t] = b_ct[t]; s_g[t] = gamma[t]; s_be[t] = beta[t]; }
    __syncthreads();

    // ---- analytic GroupNorm stats (wave 0) ----
    if (t < 64) {
        int c = t;
        float sw  = p_sw[c]  + p_sw[64 + c]  + p_sw[128 + c]  + p_sw[192 + c];
        float sw2 = p_sw2[c] + p_sw2[64 + c] + p_sw2[128 + c] + p_sw2[192 + c];
        float sx  = ws[WS_SX  + n * 64 + c];
        float sx2 = ws[WS_SX2 + n * 64 + c];
        float bc  = s_b[c];
        float ty  = sw  * sx  + 262144.f * bc;
        float ty2 = sw2 * sx2 + 2.f * bc * sw * sx + 262144.f * bc * bc;
        for (int off = 32; off; off >>= 1) {
            ty  += __shfl_down(ty, off);
            ty2 += __shfl_down(ty2, off);
        }
        if (t == 0) {
            float mean = ty * (1.f / 16777216.f);
            float var  = ty2 * (1.f / 16777216.f) - mean * mean;
            s_mi[0] = mean;
            s_mi[1] = rsqrtf(var + 1e-5f);
        }
    }
    __syncthreads();

    float mean = s_mi[0], inv = s_mi[1];
    // ---- A[o][c] = w_pw[o,c] * gamma[c] * inv  (all threads, 16 each) ----
    for (int k = 0; k < 16; ++k) {
        int idx = t + k * 256;
        int c = idx & 63;
        sA[(idx >> 6) * 68 + c] = w_pw[idx] * s_g[c] * inv;
    }
    // ---- K[o] = sum_c w_pw[o,c] * (g[c]*inv*(b[c]-mean) + beta[c]) ----
    if (t < 64) {
        int o = t;
        const f32x4* wp = (const f32x4*)(w_pw + o * 64);
        float k = 0.f;
        for (int r = 0; r < 16; ++r) {
            f32x4 v = wp[r];
            for (int e = 0; e < 4; ++e) {
                int c = r * 4 + e;
                k += v[e] * (s_g[c] * inv * (s_b[c] - mean) + s_be[c]);
            }
        }
        sK[o] = k;
    }
    __syncthreads();

    int lane = t & 63;
    int wid  = t >> 6;          // wave id = j
    int colq = lane & 15;
    int quad = lane >> 4;

    // ---- A fragments (b-operand): lane holds A[o=mt*16+colq][c=kt*32+quad*8+j] ----
    s16x8 afrag[4][2];
    for (int mt = 0; mt < 4; ++mt) {
        int o = mt * 16 + colq;
        for (int kt = 0; kt < 2; ++kt) {
            int c0 = kt * 32 + quad * 8;
            const float* ap = &sA[o * 68 + c0];
            f32x4 f0 = *(const f32x4*)ap;
            f32x4 f1 = *(const f32x4*)(ap + 4);
            s16x8 fr;
            fr[0] = (short)f2bf(f0[0]); fr[1] = (short)f2bf(f0[1]);
            fr[2] = (short)f2bf(f0[2]); fr[3] = (short)f2bf(f0[3]);
            fr[4] = (short)f2bf(f1[0]); fr[5] = (short)f2bf(f1[1]);
            fr[6] = (short)f2bf(f1[2]); fr[7] = (short)f2bf(f1[3]);
            afrag[mt][kt] = fr;
        }
    }
    // acc init: lane's column is o = mt*16+colq, all 4 row-regs share K[o]
    f32x4 kinit[4];
    for (int mt = 0; mt < 4; ++mt) {
        float kv = sK[mt * 16 + colq];
        kinit[mt][0] = kv; kinit[mt][1] = kv; kinit[mt][2] = kv; kinit[mt][3] = kv;
    }
    __syncthreads();   // sA (aliased with stg) fully consumed by all waves

    size_t base_n = (size_t)n << 24;   // n * 64 * 262144
    size_t rgn    = (size_t)(dd * 4096 + hq * 1024);   // block's per-o region base

    // ---- four o-quarter passes: pass p covers o in [p*16, p*16+16) ----
    for (int p = 0; p < 4; ++p) {
        // -- compute phase: all 4 stages (h_loc) x 4 W-tiles into stg --
        #pragma unroll
        for (int s = 0; s < 4; ++s) {
            #pragma unroll
            for (int tt = 0; tt < 4; ++tt) {
                int Woff = tt * 16 + colq;
                int wi   = Woff >> 2;
                int kf   = Woff & 3;
                int ijk  = i_f * 16 + wid * 4 + kf;
                int xrow = s * 16 + wi;

                s16x8 bfrag[2];
                #pragma unroll
                for (int kt = 0; kt < 2; ++kt) {
                    int c0 = kt * 32 + quad * 8;
                    u32x4 wv = *(const u32x4*)&sWb[ijk  * SWS + c0];
                    u32x4 xv = *(const u32x4*)&sXb[xrow * SWS + c0];
                    s16x8 fr;
                    for (int e = 0; e < 4; ++e) {
                        float pl = lo_bf(wv[e]) * lo_bf(xv[e]);
                        float ph = hi_bf(wv[e]) * hi_bf(xv[e]);
                        fr[2 * e]     = (short)f2bf(pl);
                        fr[2 * e + 1] = (short)f2bf(ph);
                    }
                    bfrag[kt] = fr;
                }
                f32x4 a = kinit[p];
                a = __builtin_amdgcn_mfma_f32_16x16x32_bf16(bfrag[0], afrag[p][0], a, 0, 0, 0);
                a = __builtin_amdgcn_mfma_f32_16x16x32_bf16(bfrag[1], afrag[p][1], a, 0, 0, 0);
                // stg[o_loc][q], o_loc = colq, q = s*256 + j*64 + W (== region offset)
                int q_loc = s * 256 + wid * 64 + tt * 16 + quad * 4;
                *(f32x4*)&stg[colq * STG_LD + q_loc] = a;
            }
        }
        __syncthreads();

        // -- store phase: per o, the FULL 4 KiB region as 4 back-to-back
        //    1 KiB wave stores; wave wid owns 4 consecutive o's --
        #pragma unroll
        for (int oo = 0; oo < 4; ++oo) {
            int o_loc = wid * 4 + oo;
            int o     = p * 16 + o_loc;
            const float* src = &stg[o_loc * STG_LD + lane * 4];
            float* dst = out + base_n + ((size_t)o << 18) + rgn + lane * 4;
            #pragma unroll
            for (int k = 0; k < 4; ++k) {
                f32x4 v = *(const f32x4*)(src + k * 256);
                *(f32x4*)(dst + k * 256) = v;
            }
        }
        __syncthreads();   // protect stg reuse by next pass
    }
}

extern "C" void kernel_launch(void* const* d_in, const int* in_sizes, int n_in,
                              void* d_out, int out_size, void* d_ws, size_t ws_size,
                              hipStream_t stream) {
    const float* x     = (const float*)d_in[0];
    const float* w_ct  = (const float*)d_in[1];
    const float* b_ct  = (const float*)d_in[2];
    const float* gamma = (const float*)d_in[3];
    const float* beta  = (const float*)d_in[4];
    const float* w_pw  = (const float*)d_in[5];
    float* ws  = (float*)d_ws;
    float* out = (float*)d_out;

    k_reduce<<<128, 256, 0, stream>>>(x, ws);
    k_main<<<512, 256, 0, stream>>>(x, w_ct, b_ct, gamma, beta, w_pw, ws, out);
}

// Round 6
// 150.135 us; speedup vs baseline: 1.5357x; 1.5357x over previous
//
#include <hip/hip_runtime.h>

typedef unsigned short u16;
typedef __attribute__((ext_vector_type(8))) short s16x8;
typedef __attribute__((ext_vector_type(4))) float f32x4;
typedef __attribute__((ext_vector_type(4))) unsigned int u32x4;

// f32 -> bf16 bits, round-to-nearest-even (finite values)
__device__ __forceinline__ u16 f2bf(float f) {
    unsigned u = __builtin_bit_cast(unsigned, f);
    u += 0x7fffu + ((u >> 16) & 1u);
    return (u16)(u >> 16);
}
__device__ __forceinline__ float lo_bf(unsigned v) {
    return __builtin_bit_cast(float, v << 16);
}
__device__ __forceinline__ float hi_bf(unsigned v) {
    return __builtin_bit_cast(float, v & 0xffff0000u);
}

// LGKM-only barrier: synchronizes LDS traffic WITHOUT draining vmcnt.
// __syncthreads() would force s_waitcnt vmcnt(0) before s_barrier, stalling
// every sub-phase until all global stores retire (the structural ~50% duty
// loss). Here global stores keep flowing across barriers; the only ordering
// needed is LDS write->read->rewrite, i.e. lgkmcnt(0).
__device__ __forceinline__ void bar_lgkm() {
    __builtin_amdgcn_sched_barrier(0);
    asm volatile("s_waitcnt lgkmcnt(0)" ::: "memory");
    __builtin_amdgcn_s_barrier();
    __builtin_amdgcn_sched_barrier(0);
}

// ws layout (floats): [0..127] Sx[n][c], [128..255] Sx2[n][c]
#define WS_SX   0
#define WS_SX2  128

// ---------------- Kernel 1: per-(n,c) moments of x (fp32) ----------------
__global__ __launch_bounds__(256) void k_reduce(const float* __restrict__ x,
                                                float* __restrict__ ws) {
    int nc = blockIdx.x;                       // 0..127, one 4096-elem channel each
    const f32x4* p = (const f32x4*)(x + (size_t)nc * 4096);
    int t = threadIdx.x;
    float s = 0.f, s2 = 0.f;
    for (int it = 0; it < 4; ++it) {
        f32x4 v = p[t + it * 256];
        for (int e = 0; e < 4; ++e) { s += v[e]; s2 += v[e] * v[e]; }
    }
    for (int off = 32; off; off >>= 1) {
        s  += __shfl_down(s, off);
        s2 += __shfl_down(s2, off);
    }
    __shared__ float rs[4], rs2[4];
    int lane = t & 63, wv = t >> 6;
    if (lane == 0) { rs[wv] = s; rs2[wv] = s2; }
    __syncthreads();
    if (t == 0) {
        ws[WS_SX  + nc] = rs[0] + rs[1] + rs[2] + rs[3];
        ws[WS_SX2 + nc] = rs2[0] + rs2[1] + rs2[2] + rs2[3];
    }
}

// ---------------- Kernel 2: fused stats + upsample + GN + pointwise --------
// Round 6 = Round 2 geometry (best measured: block=(n,d,h), i-major stages,
// 1 KiB/instruction store bursts) with the store path un-throttled:
//  (a) in-loop __syncthreads -> bar_lgkm(): global stores never drain inside
//      the loop; outstanding-store queue stays full (Little's law: BW = Q/L).
//  (b) sA aliased into stg: LDS 68 -> 51.7 KiB -> 3 blocks/CU (12 waves/CU),
//      more concurrent store streams, prologue bubbles hidden.
// Arithmetic is bit-identical to R0-R5 (absmax must stay 0.046875).
#define SWS 96       // sW/sX row stride in shorts (192 B: 2-way bank alias = free)
#define STG_LD 260   // staging row stride in floats (1040 B, 16B-aligned)
__global__ __launch_bounds__(256, 3) void k_main(const float* __restrict__ x,
                                              const float* __restrict__ w_ct,
                                              const float* __restrict__ b_ct,
                                              const float* __restrict__ gamma,
                                              const float* __restrict__ beta,
                                              const float* __restrict__ w_pw,
                                              const float* __restrict__ ws,
                                              float* __restrict__ out) {
    __shared__ __align__(16) u16   sWb[64 * SWS];   // [ijk][c] bf16        (12 KiB)
    __shared__ __align__(16) u16   sXb[16 * SWS];   // [w][c]   bf16        ( 3 KiB)
    __shared__ __align__(16) float stg[32 * STG_LD];// staging (32.5 KiB); sA aliases
    __shared__ float sK[64];
    __shared__ float p_sw[256], p_sw2[256];         // partial w-moments [qr][c]
    __shared__ float s_b[64], s_g[64], s_be[64];
    __shared__ float s_mi[2];                       // mean, inv_std

    float* sA = stg;   // [o][c] fp32, stride 68 (4352 floats <= 8320) — dead before stg use

    int t = threadIdx.x;
    int b = blockIdx.x;
    int n = b >> 8, d = (b >> 4) & 15, h = b & 15;

    // ---- stage w_ct (transpose + bf16 + partial moments), x row, small vecs ----
    {
        int c = t & 63, qr = t >> 6;               // 4 threads per channel
        const f32x4* wp = (const f32x4*)(w_ct + c * 64 + qr * 16);
        float sw = 0.f, sw2 = 0.f;
        for (int r = 0; r < 4; ++r) {
            f32x4 v = wp[r];
            for (int e = 0; e < 4; ++e) {
                float f = v[e];
                sw += f; sw2 += f * f;
                sWb[(qr * 16 + r * 4 + e) * SWS + c] = f2bf(f);
            }
        }
        p_sw[t] = sw; p_sw2[t] = sw2;
    }
    if (t < 64) {
        int c = t;
        const f32x4* xp = (const f32x4*)(x + ((size_t)n * 64 + c) * 4096 + d * 256 + h * 16);
        for (int r = 0; r < 4; ++r) {
            f32x4 v = xp[r];
            for (int e = 0; e < 4; ++e) sXb[(r * 4 + e) * SWS + c] = f2bf(v[e]);
        }
        s_b[c] = b_ct[c]; s_g[c] = gamma[c]; s_be[c] = beta[c];
    }
    __syncthreads();

    // ---- analytic GroupNorm stats (wave 0) ----
    if (t < 64) {
        int c = t;
        float sw  = p_sw[c]  + p_sw[64 + c]  + p_sw[128 + c]  + p_sw[192 + c];
        float sw2 = p_sw2[c] + p_sw2[64 + c] + p_sw2[128 + c] + p_sw2[192 + c];
        float sx  = ws[WS_SX  + n * 64 + c];
        float sx2 = ws[WS_SX2 + n * 64 + c];
        float bc  = s_b[c];
        float ty  = sw  * sx  + 262144.f * bc;
        float ty2 = sw2 * sx2 + 2.f * bc * sw * sx + 262144.f * bc * bc;
        for (int off = 32; off; off >>= 1) {
            ty  += __shfl_down(ty, off);
            ty2 += __shfl_down(ty2, off);
        }
        if (t == 0) {
            float mean = ty * (1.f / 16777216.f);
            float var  = ty2 * (1.f / 16777216.f) - mean * mean;
            s_mi[0] = mean;
            s_mi[1] = rsqrtf(var + 1e-5f);
        }
    }
    __syncthreads();

    float mean = s_mi[0], inv = s_mi[1];
    // ---- A[o][c] = w_pw[o,c] * gamma[c] * inv  (all threads, 16 each) ----
    for (int k = 0; k < 16; ++k) {
        int idx = t + k * 256;
        int c = idx & 63;
        sA[(idx >> 6) * 68 + c] = w_pw[idx] * s_g[c] * inv;
    }
    // ---- K[o] = sum_c w_pw[o,c] * (g[c]*inv*(b[c]-mean) + beta[c]) ----
    if (t < 64) {
        int o = t;
        const f32x4* wp = (const f32x4*)(w_pw + o * 64);
        float k = 0.f;
        for (int r = 0; r < 16; ++r) {
            f32x4 v = wp[r];
            for (int e = 0; e < 4; ++e) {
                int c = r * 4 + e;
                k += v[e] * (s_g[c] * inv * (s_b[c] - mean) + s_be[c]);
            }
        }
        sK[o] = k;
    }
    __syncthreads();

    int lane = t & 63;
    int wid  = t >> 6;          // wave id = j for compute phase
    int colq = lane & 15;
    int quad = lane >> 4;

    // ---- A fragments (b-operand): lane holds A[o=mt*16+colq][c=kt*32+quad*8+j] ----
    s16x8 afrag[4][2];
    for (int mt = 0; mt < 4; ++mt) {
        int o = mt * 16 + colq;
        for (int kt = 0; kt < 2; ++kt) {
            int c0 = kt * 32 + quad * 8;
            const float* ap = &sA[o * 68 + c0];
            f32x4 f0 = *(const f32x4*)ap;
            f32x4 f1 = *(const f32x4*)(ap + 4);
            s16x8 fr;
            fr[0] = (short)f2bf(f0[0]); fr[1] = (short)f2bf(f0[1]);
            fr[2] = (short)f2bf(f0[2]); fr[3] = (short)f2bf(f0[3]);
            fr[4] = (short)f2bf(f1[0]); fr[5] = (short)f2bf(f1[1]);
            fr[6] = (short)f2bf(f1[2]); fr[7] = (short)f2bf(f1[3]);
            afrag[mt][kt] = fr;
        }
    }
    // acc init: lane's column is o = mt*16+colq, all 4 row-regs share K[o]
    f32x4 kinit[4];
    for (int mt = 0; mt < 4; ++mt) {
        float kv = sK[mt * 16 + colq];
        kinit[mt][0] = kv; kinit[mt][1] = kv; kinit[mt][2] = kv; kinit[mt][3] = kv;
    }
    __syncthreads();   // sA (aliased with stg) fully consumed by all waves

    size_t base_n = (size_t)n << 24;   // n * 64 * 262144

    // ---- 4 stages: stage s = i covers q in [s*256, s*256+256) (all j, all W) ----
    for (int s = 0; s < 4; ++s) {
        int ij = s * 4 + wid;          // i = s, j = wid (one j per wave)
        f32x4 acc[4][4];               // [tt][mt]

        // -- compute phase: 4 tiles of 16 W, all 64 o held in registers --
        #pragma unroll
        for (int tt = 0; tt < 4; ++tt) {
            int Woff = tt * 16 + colq;
            int wi   = Woff >> 2;
            int kf   = Woff & 3;
            int ijk  = ij * 4 + kf;

            // B fragments (a-operand): lane holds B[c=kt*32+quad*8+j][q]
            s16x8 bfrag[2];
            #pragma unroll
            for (int kt = 0; kt < 2; ++kt) {
                int c0 = kt * 32 + quad * 8;
                u32x4 wv = *(const u32x4*)&sWb[ijk * SWS + c0];
                u32x4 xv = *(const u32x4*)&sXb[wi  * SWS + c0];
                s16x8 fr;
                for (int e = 0; e < 4; ++e) {
                    float pl = lo_bf(wv[e]) * lo_bf(xv[e]);
                    float ph = hi_bf(wv[e]) * hi_bf(xv[e]);
                    fr[2 * e]     = (short)f2bf(pl);
                    fr[2 * e + 1] = (short)f2bf(ph);
                }
                bfrag[kt] = fr;
            }
            #pragma unroll
            for (int mt = 0; mt < 4; ++mt) {
                f32x4 a = kinit[mt];
                a = __builtin_amdgcn_mfma_f32_16x16x32_bf16(bfrag[0], afrag[mt][0], a, 0, 0, 0);
                a = __builtin_amdgcn_mfma_f32_16x16x32_bf16(bfrag[1], afrag[mt][1], a, 0, 0, 0);
                acc[tt][mt] = a;
            }
        }

        // -- two store sub-phases: o in [ho*32, ho*32+32) --
        // per o: 256 consecutive floats = 1 KiB, one wave store instruction.
        // Barriers are LGKM-ONLY: global stores stream across sub-phases and
        // stages without ever draining vmcnt (drain only at kernel end).
        #pragma unroll
        for (int ho = 0; ho < 2; ++ho) {
            #pragma unroll
            for (int tt = 0; tt < 4; ++tt) {
                #pragma unroll
                for (int m2 = 0; m2 < 2; ++m2) {
                    int o_loc = m2 * 16 + colq;                 // o & 31
                    int q_loc = wid * 64 + tt * 16 + quad * 4;  // j*64 + W
                    *(f32x4*)&stg[o_loc * STG_LD + q_loc] = acc[tt][ho * 2 + m2];
                }
            }
            bar_lgkm();    // stg writes visible; stores from prior phases still in flight
            size_t gb = base_n + (size_t)((4 * d + s) * 4096 + 4 * h * 64 + lane * 4);
            #pragma unroll
            for (int it = 0; it < 8; ++it) {
                int o = ho * 32 + it * 4 + wid;
                f32x4 v = *(const f32x4*)&stg[(o & 31) * STG_LD + lane * 4];
                *(f32x4*)(out + gb + ((size_t)o << 18)) = v;
            }
            bar_lgkm();    // stg reads done -> safe to rewrite; vmcnt NOT drained
        }
    }
}

extern "C" void kernel_launch(void* const* d_in, const int* in_sizes, int n_in,
                              void* d_out, int out_size, void* d_ws, size_t ws_size,
                              hipStream_t stream) {
    const float* x     = (const float*)d_in[0];
    const float* w_ct  = (const float*)d_in[1];
    const float* b_ct  = (const float*)d_in[2];
    const float* gamma = (const float*)d_in[3];
    const float* beta  = (const float*)d_in[4];
    const float* w_pw  = (const float*)d_in[5];
    float* ws  = (float*)d_ws;
    float* out = (float*)d_out;

    k_reduce<<<128, 256, 0, stream>>>(x, ws);
    k_main<<<512, 256, 0, stream>>>(x, w_ct, b_ct, gamma, beta, w_pw, ws, out);
}